// Round 2
// baseline (481.532 us; speedup 1.0000x reference)
//
#include <hip/hip_runtime.h>
#include <hip/hip_bf16.h>
#include <math.h>

#define N_TOK 4096
#define DIM 512
#define IDIM 2048
#define NEXP 8

typedef __attribute__((ext_vector_type(8))) short bf16x8;
typedef __attribute__((ext_vector_type(4))) float floatx4;

__device__ __forceinline__ short f2bf(float f) {
  unsigned int u;
  __builtin_memcpy(&u, &f, 4);
  u += 0x7fff + ((u >> 16) & 1);  // round-to-nearest-even
  return (short)(u >> 16);
}

__device__ __forceinline__ bf16x8 ld8f(const float* __restrict__ p) {
  float4 a = *(const float4*)p;
  float4 b = *(const float4*)(p + 4);
  bf16x8 v;
  v[0] = f2bf(a.x); v[1] = f2bf(a.y); v[2] = f2bf(a.z); v[3] = f2bf(a.w);
  v[4] = f2bf(b.x); v[5] = f2bf(b.y); v[6] = f2bf(b.z); v[7] = f2bf(b.w);
  return v;
}

// ---------------- gate: fp32 logits (fp64 acc) -> argmax expert per token ----
__global__ __launch_bounds__(256) void gate_kernel(
    const float* __restrict__ x, const float* __restrict__ gw,
    int* __restrict__ expert_id, int* __restrict__ counts) {
  int tid = threadIdx.x;
  int trow = tid >> 3;   // 32 tokens per block
  int e = tid & 7;       // 8 experts
  int tok = blockIdx.x * 32 + trow;
  const float* xr = x + (long)tok * DIM;
  const float* wr = gw + e * DIM;
  double s = 0.0;
  for (int k = 0; k < DIM; k += 4) {
    float4 xv = *(const float4*)(xr + k);
    float4 wv = *(const float4*)(wr + k);
    s += (double)xv.x * wv.x + (double)xv.y * wv.y +
         (double)xv.z * wv.z + (double)xv.w * wv.w;
  }
  __shared__ double lg[32][8];
  lg[trow][e] = s;
  __syncthreads();
  if (e == 0) {
    double best = lg[trow][0];
    int bi = 0;
#pragma unroll
    for (int j = 1; j < 8; j++) {   // strict > keeps lowest index on ties (top_k semantics)
      double v = lg[trow][j];
      if (v > best) { best = v; bi = j; }
    }
    expert_id[tok] = bi;
    atomicAdd(&counts[bi], 1);
  }
}

// ---------------- scan counts + scatter token ids grouped by expert ---------
__global__ __launch_bounds__(256) void scan_scatter(
    const int* __restrict__ expert_id, const int* __restrict__ counts,
    int* __restrict__ offsets, int* __restrict__ cursors, int* __restrict__ perm) {
  if (threadIdx.x == 0) {
    int acc = 0;
    for (int e = 0; e < NEXP; e++) {
      offsets[e] = acc;
      cursors[e] = acc;
      acc += counts[e];
    }
  }
  __syncthreads();
  for (int t = threadIdx.x; t < N_TOK; t += 256) {
    int e = expert_id[t];
    int slot = atomicAdd(&cursors[e], 1);
    perm[slot] = t;
  }
}

// ---------------- generic B^T GEMM with per-mode gather/epilogue ------------
// MODE 0: routed stage1  h = silu(Xe@w1^T)*(Xe@w3^T)      A=x(f32) gathered, dual-B, BN=64
// MODE 1: shared stage1  g = gelu(X@sw1^T)                 A=x(f32),          BN=128
// MODE 2: routed stage2  y_r[tok] = He@w2^T (f32 scatter)  A=h(bf16) sorted,  BN=128
// MODE 3: shared stage2  out = f32(y_r + G@sw2^T)          A=g(bf16),         BN=128
template <int MODE>
__global__ __launch_bounds__(256) void gemm_kernel(
    const float* __restrict__ Af, const short* __restrict__ Ab,
    const float* __restrict__ B1, const float* __restrict__ B2,
    short* __restrict__ Cb, float* __restrict__ Cf, float* __restrict__ Co,
    const int* __restrict__ counts, const int* __restrict__ offsets,
    const int* __restrict__ perm) {
  constexpr int K = (MODE <= 1) ? DIM : IDIM;
  constexpr int BN = (MODE == 0) ? 64 : 128;
  constexpr int NB = (MODE == 0) ? 2 : 1;
  constexpr int BM = 128, BK = 32;
  constexpr int LS = BK + 8;  // padded LDS stride (elements)
  constexpr int WN = BN / 2;
  constexpr int NF = WN / 16;
  constexpr bool A_F32 = (MODE <= 1);

  __shared__ short Al[BM * LS];
  __shared__ short Bl[NB][BN * LS];

  int e = blockIdx.z;
  int cnt, base;
  if constexpr (MODE == 0 || MODE == 2) {
    cnt = counts[e];
    base = offsets[e];
    if ((int)blockIdx.y * BM >= cnt) return;
  } else {
    cnt = N_TOK;
    base = 0;
  }

  const float* Bp[NB];
  if constexpr (MODE == 0) {
    Bp[0] = B1 + (long)e * IDIM * DIM;
    Bp[1] = B2 + (long)e * IDIM * DIM;
  } else if constexpr (MODE == 2) {
    Bp[0] = B1 + (long)e * DIM * IDIM;
  } else {
    Bp[0] = B1;
  }

  int row0 = blockIdx.y * BM;
  int n0 = blockIdx.x * BN;
  int tid = threadIdx.x;
  int lane = tid & 63;
  int wid = tid >> 6;
  int wm = wid >> 1, wn = wid & 1;  // 2x2 wave grid, wave tile 64 x WN

  // A staging plan: 128x32 elems = 512 chunks of 8 -> 2 per thread
  const float* aptrf[2];
  const short* aptrb[2];
  bool aval[2];
  int aoff[2];
#pragma unroll
  for (int i = 0; i < 2; i++) {
    int c = tid + i * 256;
    int r = c >> 2, kk = (c & 3) * 8;
    int srow = row0 + r;
    bool v = srow < cnt;
    int grow;
    if constexpr (MODE == 0) {
      int pi = base + srow;
      if (pi > N_TOK - 1) pi = N_TOK - 1;
      grow = v ? perm[pi] : 0;
    } else if constexpr (MODE == 2) {
      grow = base + srow;
      if (grow > N_TOK - 1) grow = N_TOK - 1;
    } else {
      grow = srow;
    }
    aval[i] = v;
    if constexpr (A_F32) aptrf[i] = Af + (long)grow * K + kk;
    else                 aptrb[i] = Ab + (long)grow * K + kk;
    aoff[i] = r * LS + kk;
  }
  constexpr int BL = (BN * BK / 8) / 256;  // chunks per thread per B matrix
  const float* bptr[NB][BL];
  int boff[BL];
#pragma unroll
  for (int i = 0; i < BL; i++) {
    int c = tid + i * 256;
    int r = c >> 2, kk = (c & 3) * 8;
    boff[i] = r * LS + kk;
#pragma unroll
    for (int m = 0; m < NB; m++) bptr[m][i] = Bp[m] + (long)(n0 + r) * K + kk;
  }

  floatx4 acc[NB][4][NF];
#pragma unroll
  for (int m = 0; m < NB; m++)
#pragma unroll
    for (int i = 0; i < 4; i++)
#pragma unroll
      for (int j = 0; j < NF; j++) acc[m][i][j] = (floatx4)0.f;

  for (int kc = 0; kc < K; kc += BK) {
#pragma unroll
    for (int i = 0; i < 2; i++) {
      bf16x8 v = (bf16x8)0;
      if (aval[i]) {
        if constexpr (A_F32) v = ld8f(aptrf[i] + kc);
        else                 v = *(const bf16x8*)(aptrb[i] + kc);
      }
      *(bf16x8*)&Al[aoff[i]] = v;
    }
#pragma unroll
    for (int m = 0; m < NB; m++)
#pragma unroll
      for (int i = 0; i < BL; i++) {
        bf16x8 v = ld8f(bptr[m][i] + kc);
        *(bf16x8*)&Bl[m][boff[i]] = v;
      }
    __syncthreads();

    bf16x8 af[4];
#pragma unroll
    for (int mf = 0; mf < 4; mf++) {
      int r = wm * 64 + mf * 16 + (lane & 15);
      af[mf] = *(const bf16x8*)&Al[r * LS + (lane >> 4) * 8];
    }
#pragma unroll
    for (int m = 0; m < NB; m++)
#pragma unroll
      for (int nf = 0; nf < NF; nf++) {
        int cc = wn * WN + nf * 16 + (lane & 15);
        bf16x8 bfv = *(const bf16x8*)&Bl[m][cc * LS + (lane >> 4) * 8];
#pragma unroll
        for (int mf = 0; mf < 4; mf++)
          acc[m][mf][nf] = __builtin_amdgcn_mfma_f32_16x16x32_bf16(
              af[mf], bfv, acc[m][mf][nf], 0, 0, 0);
      }
    __syncthreads();
  }

  // epilogue: C/D mapping col = lane&15, row = quad*4 + reg (m89-verified)
  int quad = lane >> 4;
  int colb = n0 + wn * WN + (lane & 15);
#pragma unroll
  for (int mf = 0; mf < 4; mf++)
#pragma unroll
    for (int r = 0; r < 4; r++) {
      int srow = row0 + wm * 64 + mf * 16 + quad * 4 + r;
      if (srow >= cnt) continue;
      if constexpr (MODE == 0) {
        long ro = (long)(base + srow) * IDIM;
#pragma unroll
        for (int nf = 0; nf < NF; nf++) {
          float a1 = acc[0][mf][nf][r];
          float a3 = acc[1][mf][nf][r];
          float hv = (a1 / (1.f + __expf(-a1))) * a3;  // silu(a1)*a3
          Cb[ro + colb + nf * 16] = f2bf(hv);
        }
      } else if constexpr (MODE == 1) {
        long ro = (long)srow * IDIM;
#pragma unroll
        for (int nf = 0; nf < NF; nf++) {
          float v = acc[0][mf][nf][r];
          float gv = 0.5f * v * (1.f + erff(v * 0.70710678118f));  // exact gelu
          Cb[ro + colb + nf * 16] = f2bf(gv);
        }
      } else if constexpr (MODE == 2) {
        int tok = perm[base + srow];
        long ro = (long)tok * DIM;
#pragma unroll
        for (int nf = 0; nf < NF; nf++) Cf[ro + colb + nf * 16] = acc[0][mf][nf][r];
      } else {
        long ro = (long)srow * DIM;
#pragma unroll
        for (int nf = 0; nf < NF; nf++) {
          float v = Cf[ro + colb + nf * 16] + acc[0][mf][nf][r];
          Co[ro + colb + nf * 16] = v;
        }
      }
    }
}

extern "C" void kernel_launch(void* const* d_in, const int* in_sizes, int n_in,
                              void* d_out, int out_size, void* d_ws, size_t ws_size,
                              hipStream_t stream) {
  const float* x = (const float*)d_in[0];
  const float* gate_w = (const float*)d_in[1];
  const float* w1 = (const float*)d_in[2];
  const float* w2 = (const float*)d_in[3];
  const float* w3 = (const float*)d_in[4];
  const float* sw1 = (const float*)d_in[5];
  const float* sw2 = (const float*)d_in[6];
  float* out = (float*)d_out;

  char* ws = (char*)d_ws;
  int* counts = (int*)ws;            // 8
  int* offsets = counts + 8;         // 8
  int* cursors = offsets + 8;        // 8
  int* expert_id = cursors + 8;      // 4096
  int* perm = expert_id + N_TOK;     // 4096
  short* h = (short*)(ws + 65536);                    // [N_TOK, IDIM] bf16, sorted rows
  short* g = h + (size_t)N_TOK * IDIM;                // [N_TOK, IDIM] bf16
  float* y_r = (float*)(g + (size_t)N_TOK * IDIM);    // [N_TOK, DIM] f32, token order

  hipMemsetAsync(counts, 0, 8 * sizeof(int), stream);
  gate_kernel<<<N_TOK / 32, 256, 0, stream>>>(x, gate_w, expert_id, counts);
  scan_scatter<<<1, 256, 0, stream>>>(expert_id, counts, offsets, cursors, perm);
  // routed stage1: h = silu(Xe@w1^T)*(Xe@w3^T)
  gemm_kernel<0><<<dim3(IDIM / 64, N_TOK / 128, NEXP), 256, 0, stream>>>(
      x, nullptr, w1, w3, h, nullptr, nullptr, counts, offsets, perm);
  // shared stage1: g = gelu(X@sw1^T)
  gemm_kernel<1><<<dim3(IDIM / 128, N_TOK / 128, 1), 256, 0, stream>>>(
      x, nullptr, sw1, nullptr, g, nullptr, nullptr, counts, offsets, perm);
  // routed stage2: y_r[tok] = He@w2^T
  gemm_kernel<2><<<dim3(DIM / 128, N_TOK / 128, NEXP), 256, 0, stream>>>(
      nullptr, h, w2, nullptr, nullptr, y_r, nullptr, counts, offsets, perm);
  // shared stage2 + combine: out = f32(y_r + G@sw2^T)
  gemm_kernel<3><<<dim3(DIM / 128, N_TOK / 128, 1), 256, 0, stream>>>(
      nullptr, g, sw2, nullptr, nullptr, y_r, out, counts, offsets, perm);
}

// Round 3
// 379.302 us; speedup vs baseline: 1.2695x; 1.2695x over previous
//
#include <hip/hip_runtime.h>
#include <hip/hip_bf16.h>
#include <math.h>

#define N_TOK 4096
#define DIM 512
#define IDIM 2048
#define NEXP 8

typedef __attribute__((ext_vector_type(8))) short bf16x8;
typedef __attribute__((ext_vector_type(4))) float floatx4;

__device__ __forceinline__ short f2bf(float f) {
  unsigned int u;
  __builtin_memcpy(&u, &f, 4);
  u += 0x7fff + ((u >> 16) & 1);  // round-to-nearest-even
  return (short)(u >> 16);
}

__device__ __forceinline__ bf16x8 ld8f(const float* __restrict__ p) {
  float4 a = *(const float4*)p;
  float4 b = *(const float4*)(p + 4);
  bf16x8 v;
  v[0] = f2bf(a.x); v[1] = f2bf(a.y); v[2] = f2bf(a.z); v[3] = f2bf(a.w);
  v[4] = f2bf(b.x); v[5] = f2bf(b.y); v[6] = f2bf(b.z); v[7] = f2bf(b.w);
  return v;
}

// ---------------- gate: fp32 logits (fp64 acc) -> argmax expert per token ----
__global__ __launch_bounds__(256) void gate_kernel(
    const float* __restrict__ x, const float* __restrict__ gw,
    int* __restrict__ expert_id, int* __restrict__ counts) {
  int tid = threadIdx.x;
  int trow = tid >> 3;   // 32 tokens per block
  int e = tid & 7;       // 8 experts
  int tok = blockIdx.x * 32 + trow;
  const float* xr = x + (long)tok * DIM;
  const float* wr = gw + e * DIM;
  double s = 0.0;
  for (int k = 0; k < DIM; k += 4) {
    float4 xv = *(const float4*)(xr + k);
    float4 wv = *(const float4*)(wr + k);
    s += (double)xv.x * wv.x + (double)xv.y * wv.y +
         (double)xv.z * wv.z + (double)xv.w * wv.w;
  }
  __shared__ double lg[32][8];
  lg[trow][e] = s;
  __syncthreads();
  if (e == 0) {
    double best = lg[trow][0];
    int bi = 0;
#pragma unroll
    for (int j = 1; j < 8; j++) {   // strict > keeps lowest index on ties
      double v = lg[trow][j];
      if (v > best) { best = v; bi = j; }
    }
    expert_id[tok] = bi;
    atomicAdd(&counts[bi], 1);
  }
}

// ------- scan counts + dense tile tables + scatter token ids by expert ------
// nmeta[0] = #tiles at BM=128, nmeta[1] = #tiles at BM=64
__global__ __launch_bounds__(256) void scan_scatter(
    const int* __restrict__ expert_id, const int* __restrict__ counts,
    int* __restrict__ offsets, int* __restrict__ cursors, int* __restrict__ nmeta,
    int* __restrict__ t128e, int* __restrict__ t128r,
    int* __restrict__ t64e, int* __restrict__ t64r, int* __restrict__ perm) {
  if (threadIdx.x == 0) {
    int acc = 0;
    for (int e = 0; e < NEXP; e++) {
      offsets[e] = acc;
      cursors[e] = acc;
      acc += counts[e];
    }
    int n1 = 0, n2 = 0;
    for (int e = 0; e < NEXP; e++)
      for (int r = 0; r < counts[e]; r += 128) { t128e[n1] = e; t128r[n1] = r; n1++; }
    for (int e = 0; e < NEXP; e++)
      for (int r = 0; r < counts[e]; r += 64) { t64e[n2] = e; t64r[n2] = r; n2++; }
    nmeta[0] = n1;
    nmeta[1] = n2;
  }
  __syncthreads();
  for (int t = threadIdx.x; t < N_TOK; t += 256) {
    int e = expert_id[t];
    int slot = atomicAdd(&cursors[e], 1);
    perm[slot] = t;
  }
}

// ---------------- generic B^T GEMM with per-mode gather/epilogue ------------
// MODE 0: h = silu(Xe@w1^T)*(Xe@w3^T)   A=x(f32) gather,  tile table 128, dual-B
// MODE 1: g = gelu(X@sw1^T)              A=x(f32) dense
// MODE 2: out += He@w2^T (atomic f32)    A=h(bf16) sorted, tile table 64, split-K
// MODE 3: out += G@sw2^T (atomic f32)    A=g(bf16) dense,  split-K
template <int MODE, int BM, int BN, int SK>
__global__ __launch_bounds__(256) void gemm_kernel(
    const float* __restrict__ Af, const short* __restrict__ Ab,
    const float* __restrict__ B1, const float* __restrict__ B2,
    short* __restrict__ Cb, float* __restrict__ Co,
    const int* __restrict__ counts, const int* __restrict__ offsets,
    const int* __restrict__ nmeta,
    const int* __restrict__ te, const int* __restrict__ tr,
    const int* __restrict__ perm) {
  constexpr int K = (MODE <= 1) ? DIM : IDIM;
  constexpr int NB = (MODE == 0) ? 2 : 1;
  constexpr int BK = 32;
  constexpr int LS = BK + 8;       // padded LDS stride (elements)
  constexpr int MF = BM / 32;      // 16-row frags per wave (wave tile BM/2 x BN/2)
  constexpr int NF = BN / 32;
  constexpr int ACH = BM / 64;     // A staging chunks of 8 per thread
  constexpr int BL = BN / 64;      // B staging chunks per matrix per thread
  constexpr bool A_F32 = (MODE <= 1);

  __shared__ short Al[BM * LS];
  __shared__ short Bl[NB][BN * LS];

  int e, cnt, base, row0;
  if constexpr (MODE == 0 || MODE == 2) {
    int t = blockIdx.y;
    if (t >= nmeta[MODE == 0 ? 0 : 1]) return;
    e = te[t];
    row0 = tr[t];
    cnt = counts[e];
    base = offsets[e];
  } else {
    e = 0;
    cnt = N_TOK;
    base = 0;
    row0 = blockIdx.y * BM;
  }

  const float* Bp[NB];
  if constexpr (MODE == 0) {
    Bp[0] = B1 + (long)e * IDIM * DIM;
    Bp[1] = B2 + (long)e * IDIM * DIM;
  } else if constexpr (MODE == 2) {
    Bp[0] = B1 + (long)e * DIM * IDIM;
  } else {
    Bp[0] = B1;
  }

  int n0 = blockIdx.x * BN;
  int tid = threadIdx.x;
  int lane = tid & 63;
  int wid = tid >> 6;
  int wm = wid >> 1, wn = wid & 1;  // 2x2 wave grid

  const float* aptrf[ACH];
  const short* aptrb[ACH];
  bool aval[ACH];
  int aoff[ACH];
#pragma unroll
  for (int i = 0; i < ACH; i++) {
    int c = tid + i * 256;
    int r = c >> 2, kk = (c & 3) * 8;
    int srow = row0 + r;
    bool v = srow < cnt;
    int grow;
    if constexpr (MODE == 0) {
      int pi = base + srow;
      if (pi > N_TOK - 1) pi = N_TOK - 1;
      grow = v ? perm[pi] : 0;
    } else if constexpr (MODE == 2) {
      grow = base + srow;
      if (grow > N_TOK - 1) grow = N_TOK - 1;
    } else {
      grow = srow;
    }
    aval[i] = v;
    if constexpr (A_F32) aptrf[i] = Af + (long)grow * K + kk;
    else                 aptrb[i] = Ab + (long)grow * K + kk;
    aoff[i] = r * LS + kk;
  }
  const float* bptr[NB][BL];
  int boff[BL];
#pragma unroll
  for (int i = 0; i < BL; i++) {
    int c = tid + i * 256;
    int r = c >> 2, kk = (c & 3) * 8;
    boff[i] = r * LS + kk;
#pragma unroll
    for (int m = 0; m < NB; m++) bptr[m][i] = Bp[m] + (long)(n0 + r) * K + kk;
  }

  floatx4 acc[NB][MF][NF];
#pragma unroll
  for (int m = 0; m < NB; m++)
#pragma unroll
    for (int i = 0; i < MF; i++)
#pragma unroll
      for (int j = 0; j < NF; j++) acc[m][i][j] = (floatx4)0.f;

  constexpr int KSEG = K / SK;
  int kb0 = (SK > 1) ? (int)blockIdx.z * KSEG : 0;
  for (int kc = kb0; kc < kb0 + KSEG; kc += BK) {
#pragma unroll
    for (int i = 0; i < ACH; i++) {
      bf16x8 v = (bf16x8)0;
      if (aval[i]) {
        if constexpr (A_F32) v = ld8f(aptrf[i] + kc);
        else                 v = *(const bf16x8*)(aptrb[i] + kc);
      }
      *(bf16x8*)&Al[aoff[i]] = v;
    }
#pragma unroll
    for (int m = 0; m < NB; m++)
#pragma unroll
      for (int i = 0; i < BL; i++) {
        bf16x8 v = ld8f(bptr[m][i] + kc);
        *(bf16x8*)&Bl[m][boff[i]] = v;
      }
    __syncthreads();

    bf16x8 af[MF];
#pragma unroll
    for (int mf = 0; mf < MF; mf++) {
      int r = wm * (BM / 2) + mf * 16 + (lane & 15);
      af[mf] = *(const bf16x8*)&Al[r * LS + (lane >> 4) * 8];
    }
#pragma unroll
    for (int m = 0; m < NB; m++)
#pragma unroll
      for (int nf = 0; nf < NF; nf++) {
        int cc = wn * (BN / 2) + nf * 16 + (lane & 15);
        bf16x8 bfv = *(const bf16x8*)&Bl[m][cc * LS + (lane >> 4) * 8];
#pragma unroll
        for (int mf = 0; mf < MF; mf++)
          acc[m][mf][nf] = __builtin_amdgcn_mfma_f32_16x16x32_bf16(
              af[mf], bfv, acc[m][mf][nf], 0, 0, 0);
      }
    __syncthreads();
  }

  // epilogue: C/D mapping col = lane&15, row = quad*4 + reg (m89-verified)
  int quad = lane >> 4;
  int colb = n0 + wn * (BN / 2) + (lane & 15);
#pragma unroll
  for (int mf = 0; mf < MF; mf++)
#pragma unroll
    for (int r = 0; r < 4; r++) {
      int srow = row0 + wm * (BM / 2) + mf * 16 + quad * 4 + r;
      if (srow >= cnt) continue;
      if constexpr (MODE == 0) {
        long ro = (long)(base + srow) * IDIM;
#pragma unroll
        for (int nf = 0; nf < NF; nf++) {
          float a1 = acc[0][mf][nf][r];
          float a3 = acc[1][mf][nf][r];
          float hv = (a1 / (1.f + __expf(-a1))) * a3;  // silu(a1)*a3
          Cb[ro + colb + nf * 16] = f2bf(hv);
        }
      } else if constexpr (MODE == 1) {
        long ro = (long)srow * IDIM;
#pragma unroll
        for (int nf = 0; nf < NF; nf++) {
          float v = acc[0][mf][nf][r];
          float gv = 0.5f * v * (1.f + erff(v * 0.70710678118f));  // exact gelu
          Cb[ro + colb + nf * 16] = f2bf(gv);
        }
      } else if constexpr (MODE == 2) {
        int tok = perm[base + srow];
        long ro = (long)tok * DIM;
#pragma unroll
        for (int nf = 0; nf < NF; nf++)
          atomicAdd(&Co[ro + colb + nf * 16], acc[0][mf][nf][r]);
      } else {
        long ro = (long)srow * DIM;
#pragma unroll
        for (int nf = 0; nf < NF; nf++)
          atomicAdd(&Co[ro + colb + nf * 16], acc[0][mf][nf][r]);
      }
    }
}

extern "C" void kernel_launch(void* const* d_in, const int* in_sizes, int n_in,
                              void* d_out, int out_size, void* d_ws, size_t ws_size,
                              hipStream_t stream) {
  const float* x = (const float*)d_in[0];
  const float* gate_w = (const float*)d_in[1];
  const float* w1 = (const float*)d_in[2];
  const float* w2 = (const float*)d_in[3];
  const float* w3 = (const float*)d_in[4];
  const float* sw1 = (const float*)d_in[5];
  const float* sw2 = (const float*)d_in[6];
  float* out = (float*)d_out;

  char* ws = (char*)d_ws;
  int* counts = (int*)ws;            // 8
  int* offsets = counts + 8;         // 8
  int* cursors = offsets + 8;        // 8
  int* nmeta = cursors + 8;          // 2 (+6 pad)
  int* t128e = nmeta + 8;            // 64
  int* t128r = t128e + 64;           // 64
  int* t64e = t128r + 64;            // 80
  int* t64r = t64e + 80;             // 80
  int* expert_id = t64r + 80;        // 4096
  int* perm = expert_id + N_TOK;     // 4096
  short* h = (short*)(ws + 65536);                    // [N_TOK, IDIM] bf16, sorted rows
  short* g = h + (size_t)N_TOK * IDIM;                // [N_TOK, IDIM] bf16, token order

  hipMemsetAsync(counts, 0, 8 * sizeof(int), stream);
  hipMemsetAsync(out, 0, (size_t)N_TOK * DIM * sizeof(float), stream);
  gate_kernel<<<N_TOK / 32, 256, 0, stream>>>(x, gate_w, expert_id, counts);
  scan_scatter<<<1, 256, 0, stream>>>(expert_id, counts, offsets, cursors, nmeta,
                                      t128e, t128r, t64e, t64r, perm);
  // routed stage1: h = silu(Xe@w1^T)*(Xe@w3^T), dense tile table (<=40 y-tiles)
  gemm_kernel<0, 128, 64, 1><<<dim3(IDIM / 64, 40), 256, 0, stream>>>(
      x, nullptr, w1, w3, h, nullptr, counts, offsets, nmeta, t128e, t128r, perm);
  // shared stage1: g = gelu(X@sw1^T)
  gemm_kernel<1, 128, 128, 1><<<dim3(IDIM / 128, N_TOK / 128), 256, 0, stream>>>(
      x, nullptr, sw1, nullptr, g, nullptr, counts, offsets, nmeta, t128e, t128r, perm);
  // routed stage2: out += He@w2^T (atomic, split-K=2, <=72 y-tiles)
  gemm_kernel<2, 64, 128, 2><<<dim3(DIM / 128, 72, 2), 256, 0, stream>>>(
      nullptr, h, w2, nullptr, nullptr, out, counts, offsets, nmeta, t64e, t64r, perm);
  // shared stage2: out += G@sw2^T (atomic, split-K=2)
  gemm_kernel<3, 64, 128, 2><<<dim3(DIM / 128, N_TOK / 64, 2), 256, 0, stream>>>(
      nullptr, g, sw2, nullptr, nullptr, out, counts, offsets, nmeta, t64e, t64r, perm);
}

// Round 4
// 332.829 us; speedup vs baseline: 1.4468x; 1.1396x over previous
//
#include <hip/hip_runtime.h>
#include <hip/hip_bf16.h>
#include <math.h>

#define N_TOK 4096
#define DIM 512
#define IDIM 2048
#define NEXP 8

typedef __attribute__((ext_vector_type(8))) short bf16x8;
typedef __attribute__((ext_vector_type(4))) float floatx4;

__device__ __forceinline__ short f2bf(float f) {
  unsigned int u;
  __builtin_memcpy(&u, &f, 4);
  u += 0x7fff + ((u >> 16) & 1);  // round-to-nearest-even
  return (short)(u >> 16);
}

__device__ __forceinline__ bf16x8 ld8f(const float* __restrict__ p) {
  float4 a = *(const float4*)p;
  float4 b = *(const float4*)(p + 4);
  bf16x8 v;
  v[0] = f2bf(a.x); v[1] = f2bf(a.y); v[2] = f2bf(a.z); v[3] = f2bf(a.w);
  v[4] = f2bf(b.x); v[5] = f2bf(b.y); v[6] = f2bf(b.z); v[7] = f2bf(b.w);
  return v;
}

// async global->LDS DMA, 16B per lane, LDS dest = wave-uniform base + lane*16
__device__ __forceinline__ void gll(const short* g, short* l) {
  __builtin_amdgcn_global_load_lds(
      (const __attribute__((address_space(1))) void*)g,
      (__attribute__((address_space(3))) void*)l, 16, 0, 0);
}

// ---------------- convert fp32 -> bf16: x, w1, w3, sw1, sw2 -----------------
__global__ __launch_bounds__(256) void convert5(
    const float* __restrict__ x, const float* __restrict__ w1,
    const float* __restrict__ w3, const float* __restrict__ sw1,
    const float* __restrict__ sw2, short* __restrict__ xb,
    short* __restrict__ w1b, short* __restrict__ w3b,
    short* __restrict__ sw1b, short* __restrict__ sw2b) {
  const long C0 = 262144, C1 = 1310720, C2 = 2359296, C3 = 2490368, C4 = 2621440;
  for (long i = (long)blockIdx.x * 256 + threadIdx.x; i < C4; i += (long)gridDim.x * 256) {
    const float* s; short* d; long off;
    if (i < C0)      { s = x;   d = xb;   off = i; }
    else if (i < C1) { s = w1;  d = w1b;  off = i - C0; }
    else if (i < C2) { s = w3;  d = w3b;  off = i - C1; }
    else if (i < C3) { s = sw1; d = sw1b; off = i - C2; }
    else             { s = sw2; d = sw2b; off = i - C3; }
    *(bf16x8*)(d + off * 8) = ld8f(s + off * 8);
  }
}

__global__ __launch_bounds__(256) void convert1(
    const float* __restrict__ s, short* __restrict__ d, long nch) {
  for (long i = (long)blockIdx.x * 256 + threadIdx.x; i < nch; i += (long)gridDim.x * 256)
    *(bf16x8*)(d + i * 8) = ld8f(s + i * 8);
}

// ---------------- gate: fp32 logits (fp64 acc) -> argmax expert per token ----
__global__ __launch_bounds__(256) void gate_kernel(
    const float* __restrict__ x, const float* __restrict__ gw,
    int* __restrict__ expert_id, int* __restrict__ counts) {
  int tid = threadIdx.x;
  int trow = tid >> 3;
  int e = tid & 7;
  int tok = blockIdx.x * 32 + trow;
  const float* xr = x + (long)tok * DIM;
  const float* wr = gw + e * DIM;
  double s = 0.0;
  for (int k = 0; k < DIM; k += 4) {
    float4 xv = *(const float4*)(xr + k);
    float4 wv = *(const float4*)(wr + k);
    s += (double)xv.x * wv.x + (double)xv.y * wv.y +
         (double)xv.z * wv.z + (double)xv.w * wv.w;
  }
  __shared__ double lg[32][8];
  lg[trow][e] = s;
  __syncthreads();
  if (e == 0) {
    double best = lg[trow][0];
    int bi = 0;
#pragma unroll
    for (int j = 1; j < 8; j++) {
      double v = lg[trow][j];
      if (v > best) { best = v; bi = j; }
    }
    expert_id[tok] = bi;
    atomicAdd(&counts[bi], 1);
  }
}

// ------- scan counts + unified tile table (routed BM=128 + shared e=8) ------
__global__ __launch_bounds__(256) void scan_scatter(
    const int* __restrict__ expert_id, const int* __restrict__ counts,
    int* __restrict__ offsets, int* __restrict__ cursors, int* __restrict__ nmeta,
    int* __restrict__ te, int* __restrict__ tr, int* __restrict__ perm) {
  if (threadIdx.x == 0) {
    int acc = 0;
    for (int e = 0; e < NEXP; e++) {
      offsets[e] = acc;
      cursors[e] = acc;
      acc += counts[e];
    }
    int n = 0;
    for (int e = 0; e < NEXP; e++)
      for (int r = 0; r < counts[e]; r += 128) { te[n] = e; tr[n] = r; n++; }
    for (int r = 0; r < N_TOK; r += 128) { te[n] = 8; tr[n] = r; n++; }  // shared expert
    nmeta[0] = n;  // <= 72
  }
  __syncthreads();
  for (int t = threadIdx.x; t < N_TOK; t += 256) {
    int e = expert_id[t];
    int slot = atomicAdd(&cursors[e], 1);
    perm[slot] = t;
  }
}

// -------- stage1: routed h = silu(Xe@w1^T)*(Xe@w3^T); shared g = gelu(X@sw1^T)
// BM=128, 64 cols per B slot, BK=64, XOR-swizzled LDS, global_load_lds staging.
__global__ __launch_bounds__(256) void stage1(
    const short* __restrict__ xb, const short* __restrict__ w1b,
    const short* __restrict__ w3b, const short* __restrict__ sw1b,
    short* __restrict__ h, short* __restrict__ g,
    const int* __restrict__ counts, const int* __restrict__ offsets,
    const int* __restrict__ nmeta, const int* __restrict__ te,
    const int* __restrict__ tr, const int* __restrict__ perm) {
  __shared__ short Al[128 * 64];
  __shared__ short Bl[2][64 * 64];
  int t = blockIdx.y;
  if (t >= nmeta[0]) return;
  int e = te[t], row0 = tr[t];
  bool routed = (e < 8);
  int cnt = routed ? counts[e] : N_TOK;
  int base = routed ? offsets[e] : 0;
  int n0 = blockIdx.x * 64;
  int tid = threadIdx.x, lane = tid & 63, w = tid >> 6;
  int wm = w >> 1, wn = w & 1;
  const short* B1 = routed ? w1b + (long)e * IDIM * DIM : sw1b;
  const short* B2 = routed ? w3b + (long)e * IDIM * DIM : sw1b;

  // A staging plan: 1024 chunks, 4 insts/thread
  const short* ag[4];
  int lbA[4];
#pragma unroll
  for (int j = 0; j < 4; j++) {
    int c = w * 256 + j * 64 + lane;
    int row = c >> 3;
    int klog = (c & 7) ^ (row & 7);
    int srow = row0 + row;
    int gr;
    if (routed) gr = perm[base + ((srow < cnt) ? srow : (cnt - 1))];
    else        gr = srow;
    ag[j] = xb + (long)gr * DIM + klog * 8;
    lbA[j] = (w * 256 + j * 64) * 8;
  }
  // B staging plan: 512 chunks per slot, 2 insts/thread/slot
  const short* bg[2][2];
  int lbB[2];
#pragma unroll
  for (int j = 0; j < 2; j++) {
    int c = w * 128 + j * 64 + lane;
    int row = c >> 3;
    int klog = (c & 7) ^ (row & 7);
    lbB[j] = (w * 128 + j * 64) * 8;
    bg[0][j] = B1 + (long)(n0 + row) * DIM + klog * 8;
    bg[1][j] = B2 + (long)(n0 + row) * DIM + klog * 8;
  }

  floatx4 acc[2][4][2];
#pragma unroll
  for (int m = 0; m < 2; m++)
#pragma unroll
    for (int i = 0; i < 4; i++)
#pragma unroll
      for (int j = 0; j < 2; j++) acc[m][i][j] = (floatx4)0.f;

  for (int kc = 0; kc < DIM; kc += 64) {
#pragma unroll
    for (int j = 0; j < 4; j++) gll(ag[j] + kc, &Al[lbA[j]]);
#pragma unroll
    for (int j = 0; j < 2; j++) gll(bg[0][j] + kc, &Bl[0][lbB[j]]);
    if (routed) {
#pragma unroll
      for (int j = 0; j < 2; j++) gll(bg[1][j] + kc, &Bl[1][lbB[j]]);
    }
    __syncthreads();

    bf16x8 af[4][2];
#pragma unroll
    for (int mf = 0; mf < 4; mf++)
#pragma unroll
      for (int kf = 0; kf < 2; kf++) {
        int row = wm * 64 + mf * 16 + (lane & 15);
        int kp = (kf * 4 + (lane >> 4)) ^ (lane & 7);
        af[mf][kf] = *(const bf16x8*)&Al[row * 64 + kp * 8];
      }
#pragma unroll
    for (int m = 0; m < 2; m++) {
      if (m == 1 && !routed) break;
#pragma unroll
      for (int nf = 0; nf < 2; nf++)
#pragma unroll
        for (int kf = 0; kf < 2; kf++) {
          int col = wn * 32 + nf * 16 + (lane & 15);
          int kp = (kf * 4 + (lane >> 4)) ^ (lane & 7);
          bf16x8 bv = *(const bf16x8*)&Bl[m][col * 64 + kp * 8];
#pragma unroll
          for (int mf = 0; mf < 4; mf++)
            acc[m][mf][nf] = __builtin_amdgcn_mfma_f32_16x16x32_bf16(
                af[mf][kf], bv, acc[m][mf][nf], 0, 0, 0);
        }
    }
    __syncthreads();
  }

  int quad = lane >> 4;
  int colb = n0 + wn * 32 + (lane & 15);
#pragma unroll
  for (int mf = 0; mf < 4; mf++)
#pragma unroll
    for (int r = 0; r < 4; r++) {
      int srow = row0 + wm * 64 + mf * 16 + quad * 4 + r;
      if (srow >= cnt) continue;
      if (routed) {
        long ro = (long)(base + srow) * IDIM + colb;
#pragma unroll
        for (int nf = 0; nf < 2; nf++) {
          float a1 = acc[0][mf][nf][r];
          float a3 = acc[1][mf][nf][r];
          h[ro + nf * 16] = f2bf((a1 / (1.f + __expf(-a1))) * a3);
        }
      } else {
        long ro = (long)srow * IDIM + colb;
#pragma unroll
        for (int nf = 0; nf < 2; nf++) {
          float v = acc[0][mf][nf][r];
          g[ro + nf * 16] = f2bf(0.5f * v * (1.f + erff(v * 0.70710678118f)));
        }
      }
    }
}

// -------- stage2: out += He@w2^T (scatter) + G@sw2^T, split-K=4, atomics ----
__global__ __launch_bounds__(256) void stage2(
    const short* __restrict__ h, const short* __restrict__ g,
    const short* __restrict__ w2b, const short* __restrict__ sw2b,
    float* __restrict__ out, const int* __restrict__ counts,
    const int* __restrict__ offsets, const int* __restrict__ nmeta,
    const int* __restrict__ te, const int* __restrict__ tr,
    const int* __restrict__ perm) {
  __shared__ short Al[128 * 64];
  __shared__ short Bl[128 * 64];
  int t = blockIdx.y;
  if (t >= nmeta[0]) return;
  int e = te[t], row0 = tr[t];
  bool routed = (e < 8);
  int cnt = routed ? counts[e] : N_TOK;
  int base = routed ? offsets[e] : 0;
  const short* Asrc = routed ? h : g;
  const short* B = routed ? w2b + (long)e * DIM * IDIM : sw2b;
  int n0 = blockIdx.x * 128;
  int kb0 = blockIdx.z * 512;
  int tid = threadIdx.x, lane = tid & 63, w = tid >> 6;
  int wm = w >> 1, wn = w & 1;

  const short* ag[4];
  const short* bg[4];
  int lb[4];
#pragma unroll
  for (int j = 0; j < 4; j++) {
    int c = w * 256 + j * 64 + lane;
    int row = c >> 3;
    int klog = (c & 7) ^ (row & 7);
    int srow = row0 + row;
    int ar = routed ? base + ((srow < cnt) ? srow : (cnt - 1)) : srow;
    ag[j] = Asrc + (long)ar * IDIM + klog * 8;
    bg[j] = B + (long)(n0 + row) * IDIM + klog * 8;
    lb[j] = (w * 256 + j * 64) * 8;
  }

  floatx4 acc[4][4];
#pragma unroll
  for (int i = 0; i < 4; i++)
#pragma unroll
    for (int j = 0; j < 4; j++) acc[i][j] = (floatx4)0.f;

  for (int kc = kb0; kc < kb0 + 512; kc += 64) {
#pragma unroll
    for (int j = 0; j < 4; j++) gll(ag[j] + kc, &Al[lb[j]]);
#pragma unroll
    for (int j = 0; j < 4; j++) gll(bg[j] + kc, &Bl[lb[j]]);
    __syncthreads();

    bf16x8 af[4][2];
#pragma unroll
    for (int mf = 0; mf < 4; mf++)
#pragma unroll
      for (int kf = 0; kf < 2; kf++) {
        int row = wm * 64 + mf * 16 + (lane & 15);
        int kp = (kf * 4 + (lane >> 4)) ^ (lane & 7);
        af[mf][kf] = *(const bf16x8*)&Al[row * 64 + kp * 8];
      }
#pragma unroll
    for (int nf = 0; nf < 4; nf++)
#pragma unroll
      for (int kf = 0; kf < 2; kf++) {
        int col = wn * 64 + nf * 16 + (lane & 15);
        int kp = (kf * 4 + (lane >> 4)) ^ (lane & 7);
        bf16x8 bv = *(const bf16x8*)&Bl[col * 64 + kp * 8];
#pragma unroll
        for (int mf = 0; mf < 4; mf++)
          acc[mf][nf] = __builtin_amdgcn_mfma_f32_16x16x32_bf16(
              af[mf][kf], bv, acc[mf][nf], 0, 0, 0);
      }
    __syncthreads();
  }

  int quad = lane >> 4;
  int colb = n0 + wn * 64 + (lane & 15);
#pragma unroll
  for (int mf = 0; mf < 4; mf++)
#pragma unroll
    for (int r = 0; r < 4; r++) {
      int srow = row0 + wm * 64 + mf * 16 + quad * 4 + r;
      if (srow >= cnt) continue;
      int tok = routed ? perm[base + srow] : srow;
      long ro = (long)tok * DIM + colb;
#pragma unroll
      for (int nf = 0; nf < 4; nf++)
        atomicAdd(&out[ro + nf * 16], acc[mf][nf][r]);
    }
}

extern "C" void kernel_launch(void* const* d_in, const int* in_sizes, int n_in,
                              void* d_out, int out_size, void* d_ws, size_t ws_size,
                              hipStream_t stream) {
  const float* x = (const float*)d_in[0];
  const float* gate_w = (const float*)d_in[1];
  const float* w1 = (const float*)d_in[2];
  const float* w2 = (const float*)d_in[3];
  const float* w3 = (const float*)d_in[4];
  const float* sw1 = (const float*)d_in[5];
  const float* sw2 = (const float*)d_in[6];
  float* out = (float*)d_out;

  char* ws = (char*)d_ws;
  int* counts = (int*)ws;          // 8
  int* offsets = counts + 8;       // 8
  int* cursors = offsets + 8;      // 8
  int* nmeta = cursors + 8;        // 8
  int* te = nmeta + 8;             // 128
  int* tr = te + 128;              // 128
  int* expert_id = tr + 128;       // 4096
  int* perm = expert_id + N_TOK;   // 4096
  short* xb = (short*)(ws + 65536);                 // 4 MB   [N_TOK, DIM]
  short* h = xb + (size_t)N_TOK * DIM;              // 16 MB  [N_TOK, IDIM] sorted
  short* g = h + (size_t)N_TOK * IDIM;              // 16 MB  [N_TOK, IDIM]
  short* w1b = g + (size_t)N_TOK * IDIM;            // 16 MB  (aliased by w2b later)
  short* w3b = w1b + (size_t)NEXP * IDIM * DIM;     // 16 MB
  short* sw1b = w3b + (size_t)NEXP * IDIM * DIM;    // 2 MB
  short* sw2b = sw1b + (size_t)IDIM * DIM;          // 2 MB
  short* w2b = w1b;  // reuse: w1b dead after stage1

  hipMemsetAsync(counts, 0, 8 * sizeof(int), stream);
  hipMemsetAsync(out, 0, (size_t)N_TOK * DIM * sizeof(float), stream);
  gate_kernel<<<N_TOK / 32, 256, 0, stream>>>(x, gate_w, expert_id, counts);
  scan_scatter<<<1, 256, 0, stream>>>(expert_id, counts, offsets, cursors, nmeta,
                                      te, tr, perm);
  convert5<<<2560, 256, 0, stream>>>(x, w1, w3, sw1, sw2, xb, w1b, w3b, sw1b, sw2b);
  stage1<<<dim3(IDIM / 64, 72), 256, 0, stream>>>(
      xb, w1b, w3b, sw1b, h, g, counts, offsets, nmeta, te, tr, perm);
  convert1<<<2048, 256, 0, stream>>>(w2, w2b, (long)NEXP * DIM * IDIM / 8);
  stage2<<<dim3(DIM / 128, 72, 4), 256, 0, stream>>>(
      h, g, w2b, sw2b, out, counts, offsets, nmeta, te, tr, perm);
}